// Round 14
// baseline (49.389 us; speedup 1.0000x reference)
//
#include <hip/hip_runtime.h>

#define F_BINS  257
#define T_STEPS 65536
#define N_ACT   256
#define TM      256           // t-columns per k_gemm block
#define NBLK_G  256           // T_STEPS / TM  (1 block per CU, single pass)
#define NTHR    512           // 8 waves
#define XO_N4   4210688       // total float4 in x_out (257*65536/4)
#define XO_PB   16384         // float4 per block in-loop (512 thr * 32)
#define XO_MAIN (NBLK_G * XO_PB)   // 4194304; remainder 16384 in epilogue

typedef float f32x4 __attribute__((ext_vector_type(4)));
typedef short s16x8 __attribute__((ext_vector_type(8)));
typedef unsigned u32x4 __attribute__((ext_vector_type(4)));
typedef unsigned long long u64;

// ws layout (everything fully written every call - no memset needed):
//   [1024]   double partial[NBLK_G]    (per-block xo^2 sums)
//   [20480]  double corrp[257]         (per-f correction sums)
//   [24576]  unsigned maskp[NBLK_G*8]
//   [65536]  uchar Gfrag[147456]       (B frags, MFMA order: [kk][n][lane][16B])
#define WS_PART  1024
#define WS_CORR  20480
#define WS_MASK  24576
#define WS_GFRAG 65536

__device__ __forceinline__ unsigned short f2bf_rne(float x) {
  unsigned u = __builtin_bit_cast(unsigned, x);
  return (unsigned short)((u + 0x7FFFu + ((u >> 16) & 1u)) >> 16);
}
// bf16(hi)<<16 | bf16(lo) by truncation: one v_perm_b32
__device__ __forceinline__ unsigned pack_bf(float hi, float lo) {
  return __builtin_amdgcn_perm(__builtin_bit_cast(unsigned, hi),
                               __builtin_bit_cast(unsigned, lo), 0x07060302u);
}
// monotonic float->u32 (order-preserving, finite inputs)
__device__ __forceinline__ unsigned mono(float v) {
  unsigned u = __builtin_bit_cast(unsigned, v);
  return u ^ (unsigned)(((int)u >> 31) | (int)0x80000000);
}

// ---------------------------------------------------------------------------
// B fragments in MFMA order:
// Gfrag[((kk*16+n)*64+lane)*16] = 8 bf16 of G[f=32kk+8(lane>>4)+j][a=16n+(lane&15)]
// ---------------------------------------------------------------------------
__global__ __launch_bounds__(256) void k_prep(const float* __restrict__ G,
                                              unsigned char* __restrict__ gfrag) {
  const int u = blockIdx.x * 256 + threadIdx.x;   // 0..9215
  const int lane = u & 63, ng = (u >> 6) & 15, kk = u >> 10;
  const int r16 = lane & 15, g = lane >> 4;
  const int a = ng * 16 + r16;
  unsigned short h[8];
#pragma unroll
  for (int j = 0; j < 8; ++j) {
    const int f = kk * 32 + 8 * g + j;
    h[j] = (f < F_BINS) ? f2bf_rne(G[f * N_ACT + a]) : (unsigned short)0;
  }
  u32x4 w;
#pragma unroll
  for (int i = 0; i < 4; ++i)
    w[i] = (unsigned)h[2 * i] | ((unsigned)h[2 * i + 1] << 16);
  *(u32x4*)(gfrag + (size_t)u * 16) = w;
}

// ---------------------------------------------------------------------------
// Fused GEMM+argmax+xo^2. K-loop from R11/R12 (proven), plus interleaved
// xo^2 stream: per kk, consume the PREVIOUS iteration's 4 xo float4 loads
// and issue the next 4. Chunks 0..7 are consumed at kk=1..8; the epilogue
// adds ONLY the remainder (R13 bug: it re-added chunk 7 -> absmax 0.125).
// ---------------------------------------------------------------------------
__global__ __launch_bounds__(NTHR, 2) void k_gemm(
    const float* __restrict__ xs, const float4* __restrict__ xo4,
    const unsigned char* __restrict__ gfrag,
    unsigned* __restrict__ maskp, double* __restrict__ partial) {
  const int tid = threadIdx.x, lane = tid & 63, wv = tid >> 6;
  const int tq = wv & 3, ah = wv >> 2;
  const int g = lane >> 4, r16 = lane & 15;
  const int t0 = blockIdx.x * TM;
  const int tcol = t0 + 64 * tq + 4 * r16;

  __shared__ __align__(16) unsigned char Bb[147456];  // all 9 B kk-slices
  __shared__ u64 mbuf[2][TM];
  __shared__ unsigned lmask[8];
  __shared__ double sdw[8];
  if (tid < 8) lmask[tid] = 0u;

  // ---- stage ALL of B first (oldest in vm queue): 144 x 1KB chunks ----
#pragma unroll
  for (int i = 0; i < 18; ++i) {
    const int c = 18 * wv + i;
    const unsigned char* src = gfrag + (size_t)c * 1024 + (size_t)lane * 16;
    unsigned char* dst = &Bb[c * 1024];
    __builtin_amdgcn_global_load_lds(
        (const __attribute__((address_space(1))) unsigned*)src,
        (__attribute__((address_space(3))) unsigned*)dst, 16, 0, 0);
  }

  // A: 8 float4 into slot s (j = f-offset); one instr = 1KB/wave coalesced
#define LOAD_A4(s, kkv)                                                       \
  {                                                                           \
    _Pragma("unroll") for (int j = 0; j < 8; ++j) {                           \
      int f = 32 * (kkv) + 8 * g + j;                                         \
      if ((kkv) == 8) f = f > 256 ? 256 : f; /* Gfrag zero rows cover pad */  \
      va[s][j] = *(const float4*)(xs + (size_t)f * T_STEPS + tcol);           \
    }                                                                         \
  }

  float4 va[2][8];
  LOAD_A4(0, 0)
  LOAD_A4(1, 1)
  asm volatile("s_waitcnt vmcnt(16)" ::: "memory");  // B staged; A in flight
  __builtin_amdgcn_s_barrier();                      // all waves' B visible

  f32x4 acc[4][8];   // [tau][n]: row r -> t = t0'+4r+tau, a = 128ah+16n+r16
#pragma unroll
  for (int tau = 0; tau < 4; ++tau)
#pragma unroll
    for (int n = 0; n < 8; ++n) acc[tau][n] = (f32x4){0.f, 0.f, 0.f, 0.f};

#define MKAF(c) __builtin_bit_cast(s16x8, (u32x4){                            \
      pack_bf(va[s][1].c, va[s][0].c), pack_bf(va[s][3].c, va[s][2].c),       \
      pack_bf(va[s][5].c, va[s][4].c), pack_bf(va[s][7].c, va[s][6].c)})

  const size_t xbase = (size_t)blockIdx.x * XO_PB + tid;
  float4 xv[4];
  double ds = 0.0;

#pragma unroll
  for (int kk = 0; kk < 9; ++kk) {
    const int s = kk & 1;
    s16x8 af[4];
    af[0] = MKAF(x); af[1] = MKAF(y); af[2] = MKAF(z); af[3] = MKAF(w);
    if (kk + 2 <= 8) LOAD_A4(s, kk + 2)
    if (kk >= 1) {          // consume xo chunk kk-1 (1 iteration in flight)
      float fs = 0.f;
#pragma unroll
      for (int j = 0; j < 4; ++j) {
        fs = fmaf(xv[j].x, xv[j].x, fs); fs = fmaf(xv[j].y, xv[j].y, fs);
        fs = fmaf(xv[j].z, xv[j].z, fs); fs = fmaf(xv[j].w, xv[j].w, fs);
      }
      ds += (double)fs;
    }
    if (kk <= 7) {          // issue xo chunk kk: 4 x 1KB/wave coalesced
#pragma unroll
      for (int j = 0; j < 4; ++j)
        xv[j] = xo4[xbase + (size_t)(kk * 2048 + j * 512)];
    }
    const unsigned char* bp = &Bb[((kk * 16 + 8 * ah) * 64 + lane) * 16];
#pragma unroll
    for (int n = 0; n < 8; ++n) {
      const s16x8 bfr = *(const s16x8*)(bp + n * 1024);
#pragma unroll
      for (int tau = 0; tau < 4; ++tau)
        acc[tau][n] = __builtin_amdgcn_mfma_f32_16x16x32_bf16(
            af[tau], bfr, acc[tau][n], 0, 0, 0);
    }
  }
#undef LOAD_A4
#undef MKAF

  // ---- xo remainder: 64 float4 per block (issue early, consume later) ----
  float4 wrem = (float4){0.f, 0.f, 0.f, 0.f};
  if (tid < 64) wrem = xo4[XO_MAIN + (size_t)blockIdx.x * 64 + tid];

  // ---- argmax per row r=4g+q, t = t0 + 64tq + 4r + tau, over 128 actions --
#pragma unroll
  for (int tau = 0; tau < 4; ++tau) {
#pragma unroll
    for (int q = 0; q < 4; ++q) {
      float bv = acc[tau][0][q];
      int   bc = 128 * ah + r16;
#pragma unroll
      for (int n = 1; n < 8; ++n) {
        const int c = 128 * ah + 16 * n + r16;
        if (acc[tau][n][q] > bv) { bv = acc[tau][n][q]; bc = c; }
      }
      u64 key = ((u64)mono(bv) << 32) | (unsigned)(~bc);
#pragma unroll
      for (int m = 1; m <= 8; m <<= 1) {   // reduce over r16 (lane bits 0..3)
        const u64 ok = __shfl_xor(key, m, 64);
        if (ok > key) key = ok;
      }
      if (r16 == 0)
        mbuf[ah][64 * tq + 4 * (4 * g + q) + tau] = key;
    }
  }
  __syncthreads();
  if (tid < TM) {
    const u64 k0 = mbuf[0][tid], k1 = mbuf[1][tid];
    const u64 k = k0 >= k1 ? k0 : k1;   // tie -> lower action (ah=0, ~bc max)
    const unsigned bc = ~(unsigned)(k & 0xFFFFFFFFull);
    atomicOr(&lmask[bc >> 5], 1u << (bc & 31));
  }
  __syncthreads();
  if (tid < 8) maskp[blockIdx.x * 8 + tid] = lmask[tid];

  // ---- finish xo: ONLY the remainder (chunks 0..7 were consumed in-loop) --
  {
    float fs = 0.f;
    fs = fmaf(wrem.x, wrem.x, fs); fs = fmaf(wrem.y, wrem.y, fs);
    fs = fmaf(wrem.z, wrem.z, fs); fs = fmaf(wrem.w, wrem.w, fs);
    ds += (double)fs;
  }
#pragma unroll
  for (int off = 32; off; off >>= 1) ds += __shfl_down(ds, off);
  if (lane == 0) sdw[wv] = ds;
  __syncthreads();
  if (tid == 0) {
    double s = 0.0;
#pragma unroll
    for (int w = 0; w < 8; ++w) s += sdw[w];
    partial[blockIdx.x] = s;
  }
}

// ---------------------------------------------------------------------------
// OR-reduce per-block masks, then correction for selected columns t = a:
//   corrp[f] = sum_a sel[a] * ((G*xs)^2 - 2*(G*xs)*xo)  -- no global atomics
// ---------------------------------------------------------------------------
__global__ __launch_bounds__(256) void k_corr(
    const float* __restrict__ xs, const float* __restrict__ xo,
    const float* __restrict__ G, const unsigned* __restrict__ maskp,
    double* __restrict__ corrp) {
  __shared__ unsigned m8[8];
  const int tid = threadIdx.x;
  if (tid < 8) m8[tid] = 0u;
  __syncthreads();
  unsigned m = 0;
  for (int b = tid >> 3; b < NBLK_G; b += 32) m |= maskp[b * 8 + (tid & 7)];
  atomicOr(&m8[tid & 7], m);
  __syncthreads();
  const int f = blockIdx.x, a = tid;
  const bool sel = (m8[a >> 5] >> (a & 31)) & 1u;
  const float gv  = G[f * N_ACT + a];
  const float xsv = xs[(size_t)f * T_STEPS + a];
  const float xov = xo[(size_t)f * T_STEPS + a];
  const float gx  = gv * xsv;
  double acc = sel ? (double)(gx * (gx - 2.f * xov)) : 0.0;
#pragma unroll
  for (int off = 32; off; off >>= 1) acc += __shfl_down(acc, off);
  __shared__ double sdc[4];
  if ((tid & 63) == 0) sdc[tid >> 6] = acc;
  __syncthreads();
  if (tid == 0) corrp[f] = sdc[0] + sdc[1] + sdc[2] + sdc[3];
}

// ---------------------------------------------------------------------------
// Final reduction: partial[256] + corrp[257] -> loss
// ---------------------------------------------------------------------------
__global__ __launch_bounds__(256) void k_final(const double* __restrict__ partial,
                                               const double* __restrict__ corrp,
                                               float* __restrict__ out) {
  const int tid = threadIdx.x;
  double s = partial[tid] + corrp[tid];
  if (tid == 0) s += corrp[256];
#pragma unroll
  for (int off = 32; off; off >>= 1) s += __shfl_down(s, off);
  __shared__ double sd[4];
  if ((tid & 63) == 0) sd[tid >> 6] = s;
  __syncthreads();
  if (tid == 0)
    out[0] = (float)((sd[0] + sd[1] + sd[2] + sd[3]) /
                     ((double)F_BINS * (double)T_STEPS));
}

extern "C" void kernel_launch(void* const* d_in, const int* in_sizes, int n_in,
                              void* d_out, int out_size, void* d_ws, size_t ws_size,
                              hipStream_t stream) {
  const float* x_out    = (const float*)d_in[0];
  const float* x_source = (const float*)d_in[1];
  // d_in[2] (x_clean) is dead: argmin_a(clean_sum - proj) == argmax_a proj
  const float* G        = (const float*)d_in[3];

  char* ws = (char*)d_ws;
  double*        partial = (double*)(ws + WS_PART);
  double*        corrp   = (double*)(ws + WS_CORR);
  unsigned*      maskp   = (unsigned*)(ws + WS_MASK);
  unsigned char* gfrag   = (unsigned char*)(ws + WS_GFRAG);

  // no memset: partial, corrp, maskp, gfrag fully written every call
  k_prep <<<36, 256, 0, stream>>>(G, gfrag);
  k_gemm <<<NBLK_G, NTHR, 0, stream>>>(x_source, (const float4*)x_out,
                                       gfrag, maskp, partial);
  k_corr <<<F_BINS, 256, 0, stream>>>(x_source, x_out, G, maskp, corrp);
  k_final<<<1, 256, 0, stream>>>(partial, corrp, (float*)d_out);
}

// Round 15
// 44.684 us; speedup vs baseline: 1.1053x; 1.1053x over previous
//
#include <hip/hip_runtime.h>

#define F_BINS  257
#define T_STEPS 65536
#define N_ACT   256
#define TM      256           // t-columns per k_gemm block (8 waves x 32t)
#define NBLK_G  256           // T_STEPS / TM
#define NTHR    512           // 8 waves
#define XO_N4   4210688       // total float4 in x_out = 514 * 8192 exactly
#define XO_BLKS 514
#define PREP_BLKS 36

typedef float f32x4 __attribute__((ext_vector_type(4)));
typedef short s16x8 __attribute__((ext_vector_type(8)));
typedef unsigned u32x4 __attribute__((ext_vector_type(4)));

// ws layout (all fully written every call - no memset needed):
//   [1024]   double partial[XO_BLKS=514]  (per-block xo^2 sums)
//   [20480]  double corrp[257]            (per-f correction sums)
//   [24576]  unsigned maskp[NBLK_G*8]
//   [65536]  uchar Gfrag[147456]          (B frags: [kk][n][lane][16B])
#define WS_PART  1024
#define WS_CORR  20480
#define WS_MASK  24576
#define WS_GFRAG 65536

__device__ __forceinline__ unsigned short f2bf_rne(float x) {
  unsigned u = __builtin_bit_cast(unsigned, x);
  return (unsigned short)((u + 0x7FFFu + ((u >> 16) & 1u)) >> 16);
}
// bf16(hi)<<16 | bf16(lo) by truncation: one v_perm_b32
__device__ __forceinline__ unsigned pack_bf(float hi, float lo) {
  return __builtin_amdgcn_perm(__builtin_bit_cast(unsigned, hi),
                               __builtin_bit_cast(unsigned, lo), 0x07060302u);
}

// ---------------------------------------------------------------------------
// Fused prep + xo^2 stream (xo is independent of gfrag, so it overlaps the
// G-transpose for free instead of perturbing the GEMM loop like R13/R14).
// Blocks 0..35: Gfrag build. Blocks 36..549: xo chunks (8192 float4 each).
// ---------------------------------------------------------------------------
__global__ __launch_bounds__(256) void k_pre(
    const float* __restrict__ G, const float4* __restrict__ xo4,
    unsigned char* __restrict__ gfrag, double* __restrict__ partial) {
  const int tid = threadIdx.x;
  if (blockIdx.x < PREP_BLKS) {
    // Gfrag[((kk*16+n)*64+lane)*16] = 8 bf16 of
    //   G[f=32kk+8(lane>>4)+j][a=16n+(lane&15)], zero for f>=257
    const int u = blockIdx.x * 256 + tid;   // 0..9215
    const int lane = u & 63, ng = (u >> 6) & 15, kk = u >> 10;
    const int r16 = lane & 15, g = lane >> 4;
    const int a = ng * 16 + r16;
    unsigned short h[8];
#pragma unroll
    for (int j = 0; j < 8; ++j) {
      const int f = kk * 32 + 8 * g + j;
      h[j] = (f < F_BINS) ? f2bf_rne(G[f * N_ACT + a]) : (unsigned short)0;
    }
    u32x4 w;
#pragma unroll
    for (int i = 0; i < 4; ++i)
      w[i] = (unsigned)h[2 * i] | ((unsigned)h[2 * i + 1] << 16);
    *(u32x4*)(gfrag + (size_t)u * 16) = w;
    return;
  }
  // ---- xo^2: 16-deep register pipeline x 2 rounds, per-block partial ----
  const int b = blockIdx.x - PREP_BLKS;
  const size_t base = (size_t)b * 8192 + tid;
  double ds = 0.0;
#pragma unroll
  for (int r = 0; r < 2; ++r) {
    float4 v[16];
#pragma unroll
    for (int j = 0; j < 16; ++j) v[j] = xo4[base + (size_t)(r * 16 + j) * 256];
    float fs = 0.f;
#pragma unroll
    for (int j = 0; j < 16; ++j) {
      fs = fmaf(v[j].x, v[j].x, fs); fs = fmaf(v[j].y, v[j].y, fs);
      fs = fmaf(v[j].z, v[j].z, fs); fs = fmaf(v[j].w, v[j].w, fs);
    }
    ds += (double)fs;
  }
#pragma unroll
  for (int off = 32; off; off >>= 1) ds += __shfl_down(ds, off);
  __shared__ double sd[4];
  if ((tid & 63) == 0) sd[tid >> 6] = ds;
  __syncthreads();
  if (tid == 0) partial[b] = sd[0] + sd[1] + sd[2] + sd[3];
}

// ---------------------------------------------------------------------------
// GEMM+argmax. Wave wv (0..7) owns t in [t0+32wv, +32) x ALL 256 actions
// (two action-half passes, acc[2][8] reused). A is FULLY preloaded into
// bf16 fragments af[9][2] (72 VGPR) via float2 loads in a 4-batch sliding
// window; B (144KB) staged whole into LDS. The compute loop has zero global
// loads and zero barriers - latency lives only in the pure-BW prologue.
// Fragment t-map: lane r16 holds t = base + 2*r16 + tau (tau = float2 lane).
// ---------------------------------------------------------------------------
__global__ __launch_bounds__(NTHR, 2) void k_gemm(
    const float* __restrict__ xs, const unsigned char* __restrict__ gfrag,
    unsigned* __restrict__ maskp) {
  const int tid = threadIdx.x, lane = tid & 63, wv = tid >> 6;
  const int g = lane >> 4, r16 = lane & 15;
  const int t0 = blockIdx.x * TM;
  const int tcol = t0 + 32 * wv + 2 * r16;   // float2 load column

  __shared__ __align__(16) unsigned char Bb[147456];
  __shared__ unsigned lmask[8];
  if (tid < 8) lmask[tid] = 0u;

  // A batch: 8 float2 loads (f-rows 32kkv+8g..+8g+7 at fixed 2 t's)
#define LOADB(slot, kkv)                                                      \
  {                                                                           \
    _Pragma("unroll") for (int j = 0; j < 8; ++j) {                           \
      int f = 32 * (kkv) + 8 * g + j;                                         \
      if ((kkv) == 8) f = f > 256 ? 256 : f; /* Gfrag zero rows cover pad */  \
      va[slot][j] = *(const float2*)(xs + (size_t)f * T_STEPS + tcol);        \
    }                                                                         \
  }

  float2 va[4][8];
  LOADB(0, 0) LOADB(1, 1) LOADB(2, 2) LOADB(3, 3)
  __builtin_amdgcn_sched_barrier(0);
  // stage ALL of B (issued after batches 0-3 so waiting va[0..3] never
  // forces B retirement; issued before batches 4-8 so vmcnt(0) covers it)
#pragma unroll
  for (int i = 0; i < 18; ++i) {
    const int c = 18 * wv + i;
    const unsigned char* src = gfrag + (size_t)c * 1024 + (size_t)lane * 16;
    unsigned char* dst = &Bb[c * 1024];
    __builtin_amdgcn_global_load_lds(
        (const __attribute__((address_space(1))) unsigned*)src,
        (__attribute__((address_space(3))) unsigned*)dst, 16, 0, 0);
  }
  __builtin_amdgcn_sched_barrier(0);

  // pack all A fragments while later batches stream in
  s16x8 af[9][2];   // [kk][tau], 72 VGPR
#pragma unroll
  for (int kk = 0; kk < 9; ++kk) {
    const int b = kk & 3;
    // compiler inserts counted vmcnt for va[b] here
    af[kk][0] = __builtin_bit_cast(s16x8, (u32x4){
        pack_bf(va[b][1].x, va[b][0].x), pack_bf(va[b][3].x, va[b][2].x),
        pack_bf(va[b][5].x, va[b][4].x), pack_bf(va[b][7].x, va[b][6].x)});
    af[kk][1] = __builtin_bit_cast(s16x8, (u32x4){
        pack_bf(va[b][1].y, va[b][0].y), pack_bf(va[b][3].y, va[b][2].y),
        pack_bf(va[b][5].y, va[b][4].y), pack_bf(va[b][7].y, va[b][6].y)});
    if (kk + 4 <= 8) LOADB(b, kk + 4)
  }
#undef LOADB

  asm volatile("s_waitcnt vmcnt(0)" ::: "memory");  // B LDS writes done
  __builtin_amdgcn_s_barrier();                     // all waves' B visible

  // ---- two action-half passes; argmax folds across h in registers ----
  float bv[2][4]; int bc[2][4];
#pragma unroll
  for (int h = 0; h < 2; ++h) {
    f32x4 acc[2][8];   // [tau][n]
#pragma unroll
    for (int tau = 0; tau < 2; ++tau)
#pragma unroll
      for (int n = 0; n < 8; ++n) acc[tau][n] = (f32x4){0.f, 0.f, 0.f, 0.f};
#pragma unroll
    for (int kk = 0; kk < 9; ++kk) {
      const unsigned char* bp = &Bb[((kk * 16 + 8 * h) * 64 + lane) * 16];
#pragma unroll
      for (int n = 0; n < 8; ++n) {
        const s16x8 bfr = *(const s16x8*)(bp + n * 1024);
        acc[0][n] = __builtin_amdgcn_mfma_f32_16x16x32_bf16(
            af[kk][0], bfr, acc[0][n], 0, 0, 0);
        acc[1][n] = __builtin_amdgcn_mfma_f32_16x16x32_bf16(
            af[kk][1], bfr, acc[1][n], 0, 0, 0);
      }
    }
    // fold into running argmax: a = 128h + 16n + r16 (ascending => first-min)
#pragma unroll
    for (int n = 0; n < 8; ++n) {
      const int c = 128 * h + 16 * n + r16;
#pragma unroll
      for (int tau = 0; tau < 2; ++tau)
#pragma unroll
        for (int q = 0; q < 4; ++q) {
          const float v = acc[tau][n][q];
          if (h == 0 && n == 0) { bv[tau][q] = v; bc[tau][q] = c; }
          else if (v > bv[tau][q]) { bv[tau][q] = v; bc[tau][q] = c; }
        }
    }
  }

  // cross-lane (r16) argmax; each lane's t = t0+32wv+2*(4g+q)+tau
#pragma unroll
  for (int m = 1; m <= 8; m <<= 1) {
#pragma unroll
    for (int tau = 0; tau < 2; ++tau)
#pragma unroll
      for (int q = 0; q < 4; ++q) {
        const float ov = __shfl_xor(bv[tau][q], m);
        const int   oc = __shfl_xor(bc[tau][q], m);
        if (ov > bv[tau][q] || (ov == bv[tau][q] && oc < bc[tau][q])) {
          bv[tau][q] = ov; bc[tau][q] = oc;
        }
      }
  }
  if (r16 == 0) {
#pragma unroll
    for (int tau = 0; tau < 2; ++tau)
#pragma unroll
      for (int q = 0; q < 4; ++q)
        atomicOr(&lmask[bc[tau][q] >> 5], 1u << (bc[tau][q] & 31));
  }
  __syncthreads();
  if (tid < 8) maskp[blockIdx.x * 8 + tid] = lmask[tid];
}

// ---------------------------------------------------------------------------
// OR-reduce per-block masks, then correction for selected columns t = a:
//   corrp[f] = sum_a sel[a] * ((G*xs)^2 - 2*(G*xs)*xo)
// ---------------------------------------------------------------------------
__global__ __launch_bounds__(256) void k_corr(
    const float* __restrict__ xs, const float* __restrict__ xo,
    const float* __restrict__ G, const unsigned* __restrict__ maskp,
    double* __restrict__ corrp) {
  __shared__ unsigned m8[8];
  const int tid = threadIdx.x;
  if (tid < 8) m8[tid] = 0u;
  __syncthreads();
  unsigned m = 0;
  for (int b = tid >> 3; b < NBLK_G; b += 32) m |= maskp[b * 8 + (tid & 7)];
  atomicOr(&m8[tid & 7], m);
  __syncthreads();
  const int f = blockIdx.x, a = tid;
  const bool sel = (m8[a >> 5] >> (a & 31)) & 1u;
  const float gv  = G[f * N_ACT + a];
  const float xsv = xs[(size_t)f * T_STEPS + a];
  const float xov = xo[(size_t)f * T_STEPS + a];
  const float gx  = gv * xsv;
  double acc = sel ? (double)(gx * (gx - 2.f * xov)) : 0.0;
#pragma unroll
  for (int off = 32; off; off >>= 1) acc += __shfl_down(acc, off);
  __shared__ double sdc[4];
  if ((tid & 63) == 0) sdc[tid >> 6] = acc;
  __syncthreads();
  if (tid == 0) corrp[f] = sdc[0] + sdc[1] + sdc[2] + sdc[3];
}

// ---------------------------------------------------------------------------
// Final reduction: partial[514] + corrp[257] -> loss
// ---------------------------------------------------------------------------
__global__ __launch_bounds__(256) void k_final(const double* __restrict__ partial,
                                               const double* __restrict__ corrp,
                                               float* __restrict__ out) {
  const int tid = threadIdx.x;
  double s = partial[tid] + partial[tid + 256] + corrp[tid];
  if (tid < 2) s += partial[tid + 512];
  if (tid == 0) s += corrp[256];
#pragma unroll
  for (int off = 32; off; off >>= 1) s += __shfl_down(s, off);
  __shared__ double sd[4];
  if ((tid & 63) == 0) sd[tid >> 6] = s;
  __syncthreads();
  if (tid == 0)
    out[0] = (float)((sd[0] + sd[1] + sd[2] + sd[3]) /
                     ((double)F_BINS * (double)T_STEPS));
}

extern "C" void kernel_launch(void* const* d_in, const int* in_sizes, int n_in,
                              void* d_out, int out_size, void* d_ws, size_t ws_size,
                              hipStream_t stream) {
  const float* x_out    = (const float*)d_in[0];
  const float* x_source = (const float*)d_in[1];
  // d_in[2] (x_clean) is dead: argmin_a(clean_sum - proj) == argmax_a proj
  const float* G        = (const float*)d_in[3];

  char* ws = (char*)d_ws;
  double*        partial = (double*)(ws + WS_PART);
  double*        corrp   = (double*)(ws + WS_CORR);
  unsigned*      maskp   = (unsigned*)(ws + WS_MASK);
  unsigned char* gfrag   = (unsigned char*)(ws + WS_GFRAG);

  // no memset: partial, corrp, maskp, gfrag fully written every call
  k_pre  <<<PREP_BLKS + XO_BLKS, 256, 0, stream>>>(G, (const float4*)x_out,
                                                   gfrag, partial);
  k_gemm <<<NBLK_G, NTHR, 0, stream>>>(x_source, gfrag, maskp);
  k_corr <<<F_BINS, 256, 0, stream>>>(x_source, x_out, G, maskp, corrp);
  k_final<<<1, 256, 0, stream>>>(partial, corrp, (float*)d_out);
}